// Round 9
// baseline (172.978 us; speedup 1.0000x reference)
//
#include <hip/hip_runtime.h>
#include <math.h>

#define N 1024
#define K 16
#define RF 8        // refill depth on rescan
#define SENT 255

// (v2,f2) beats (v1,f1): larger value wins; tie -> smaller index
__device__ __forceinline__ bool better(float v2, int f2, float v1, int f1) {
    return (v2 > v1) || (v2 == v1 && f2 < f1);
}

// One reduce level via DPP (VALU latency, no DS pipe).
template<int CTRL>
__device__ __forceinline__ void dpp_step(float& v, int& f) {
    int ovi = __builtin_amdgcn_update_dpp(0, __float_as_int(v), CTRL, 0xF, 0xF, true);
    int ofi = __builtin_amdgcn_update_dpp(0, f, CTRL, 0xF, 0xF, true);
    float ov = __int_as_float(ovi);
    if (better(ov, ofi, v, f)) { v = ov; f = ofi; }
}

// Full-wave argmax on (v,f); result broadcast to all lanes.
__device__ __forceinline__ void wave_argmax(float& v, int& f) {
    dpp_step<0xB1>(v, f);
    dpp_step<0x4E>(v, f);
    dpp_step<0x141>(v, f);
    dpp_step<0x140>(v, f);
    float v0 = __int_as_float(__builtin_amdgcn_readlane(__float_as_int(v), 0));
    int   f0 = __builtin_amdgcn_readlane(f, 0);
    float v1 = __int_as_float(__builtin_amdgcn_readlane(__float_as_int(v), 16));
    int   f1 = __builtin_amdgcn_readlane(f, 16);
    float v2 = __int_as_float(__builtin_amdgcn_readlane(__float_as_int(v), 32));
    int   f2 = __builtin_amdgcn_readlane(f, 32);
    float v3 = __int_as_float(__builtin_amdgcn_readlane(__float_as_int(v), 48));
    int   f3 = __builtin_amdgcn_readlane(f, 48);
    if (better(v1, f1, v0, f0)) { v0 = v1; f0 = f1; }
    if (better(v3, f3, v2, f2)) { v2 = v3; f2 = f3; }
    if (better(v2, f2, v0, f0)) { v0 = v2; f0 = f2; }
    v = v0; f = f0;
}

// ---------------------------------------------------------------------------
// Generic top-K per row of M (val desc, idx asc). One wave per row, coalesced.
// Run on C -> rowList; run on CT -> colList.
// ---------------------------------------------------------------------------
__global__ __launch_bounds__(256) void topk_kernel(const float* __restrict__ M,
                                                   unsigned short* __restrict__ listG) {
    int row  = (blockIdx.x * blockDim.x + threadIdx.x) >> 6;
    int lane = threadIdx.x & 63;
    if (row >= N) return;
    const float* rp = M + (size_t)row * N;
    float rv[16];
    #pragma unroll
    for (int k = 0; k < 16; ++k) rv[k] = rp[(k << 6) + lane];
    unsigned excl = 0;
    for (int pass = 0; pass < K; ++pass) {
        float best = -INFINITY; int bc = N;
        #pragma unroll
        for (int k = 0; k < 16; ++k) {
            int c = (k << 6) + lane;
            if (!((excl >> k) & 1u) && rv[k] > best) { best = rv[k]; bc = c; }
        }
        wave_argmax(best, bc);
        if (lane == (bc & 63)) excl |= 1u << (bc >> 6);
        if (lane == 0) listG[row * K + pass] = (unsigned short)bc;
    }
}

// ---------------------------------------------------------------------------
// Legacy col top-K via LDS tiles (used only when ws too small for CT).
// ---------------------------------------------------------------------------
__global__ __launch_bounds__(1024) void topk_cols(const float* __restrict__ C,
                                                  unsigned short* __restrict__ colListG) {
    __shared__ float T[16][1025];
    const int t  = threadIdx.x;
    const int c0 = blockIdx.x << 4;
    const int cc = t & 15;
    const int tr = t >> 4;
    #pragma unroll
    for (int k = 0; k < 16; ++k) {
        int r = (k << 6) + tr;
        T[cc][r] = C[(size_t)r * N + c0 + cc];
    }
    __syncthreads();
    const int wave = t >> 6;
    const int lane = t & 63;
    const int c = c0 + wave;
    float rv[16];
    #pragma unroll
    for (int k = 0; k < 16; ++k) rv[k] = T[wave][(k << 6) + lane];
    unsigned excl = 0;
    for (int pass = 0; pass < K; ++pass) {
        float best = -INFINITY; int br = N;
        #pragma unroll
        for (int k = 0; k < 16; ++k) {
            int r = (k << 6) + lane;
            if (!((excl >> k) & 1u) && rv[k] > best) { best = rv[k]; br = r; }
        }
        wave_argmax(best, br);
        if (lane == (br & 63)) excl |= 1u << (br >> 6);
        if (lane == 0) colListG[c * K + pass] = (unsigned short)br;
    }
}

// ---------------------------------------------------------------------------
// Tiled transpose C -> CT (64x64 tiles via LDS).
// ---------------------------------------------------------------------------
__global__ __launch_bounds__(256) void transpose_k(const float* __restrict__ C,
                                                   float* __restrict__ CT) {
    __shared__ float T[64][65];
    const int t = threadIdx.x;
    const int tx = t & 63, ty = t >> 6;
    const int bi = blockIdx.x, bj = blockIdx.y;
    #pragma unroll
    for (int k = 0; k < 16; ++k) {
        int r = (bi << 6) + ty + (k << 2);
        T[ty + (k << 2)][tx] = C[(size_t)r * N + (bj << 6) + tx];
    }
    __syncthreads();
    #pragma unroll
    for (int k = 0; k < 16; ++k) {
        int c = (bj << 6) + ty + (k << 2);
        CT[(size_t)c * N + (bi << 6) + tx] = T[tx][ty + (k << 2)];
    }
}

// ---------------------------------------------------------------------------
// Rounds: match mutual heads; pop dead heads from LDS lists; on exhaustion,
// wave-parallel coalesced RESCAN+REFILL (depth RF) from C / CT.
// ---------------------------------------------------------------------------
__global__ __launch_bounds__(1024) void rounds_fast(const float* __restrict__ C,
                                                    const float* __restrict__ CT,
                                                    const unsigned short* __restrict__ rowListG,
                                                    const unsigned short* __restrict__ colListG,
                                                    int* __restrict__ out,
                                                    int haveCT) {
    __shared__ unsigned short rowList[N * K];   // 32 KB
    __shared__ unsigned short colList[N * K];   // 32 KB
    __shared__ unsigned short rowHead[N];
    __shared__ unsigned short colHead[N];
    __shared__ unsigned char  rowPtr[N], colPtr[N];
    __shared__ unsigned char  rowLen[N], colLen[N];
    __shared__ unsigned aliveW[N / 32], usedW[N / 32];
    __shared__ unsigned short rowQ[N], colQ[N];
    __shared__ int rqn, cqn, matched;

    const int t = threadIdx.x;
    const int lane = t & 63;
    const int wave = t >> 6;

    #pragma unroll
    for (int i = 0; i < (N * K * 2) / (16 * 1024); ++i) {
        ((uint4*)rowList)[i * 1024 + t] = ((const uint4*)rowListG)[i * 1024 + t];
        ((uint4*)colList)[i * 1024 + t] = ((const uint4*)colListG)[i * 1024 + t];
    }
    rowPtr[t] = 0; colPtr[t] = 0;
    rowLen[t] = K; colLen[t] = K;
    if (t < N / 32) { aliveW[t] = 0xFFFFFFFFu; usedW[t] = 0u; }
    if (t == 0) matched = 0;
    __syncthreads();
    rowHead[t] = rowList[t * K];
    colHead[t] = colList[t * K];
    __syncthreads();

    for (int round = 0; round < N + 8; ++round) {
        // ---- phase 1: match mutual-best pairs -----------------------------
        if ((aliveW[t >> 5] >> (t & 31)) & 1u) {
            const int c = rowHead[t];
            if ((int)colHead[c] == t) {
                out[N + t] = c;
                atomicAnd(&aliveW[t >> 5], ~(1u << (t & 31)));
                atomicOr(&usedW[c >> 5], 1u << (c & 31));
                atomicAdd(&matched, 1);
            }
        }
        if (t == 0) { rqn = 0; cqn = 0; }
        __syncthreads();                                           // B1
        const int aliveCnt = N - matched;
        if (aliveCnt <= 0) break;

        // ---- phase 2a: repair row heads (alive rows) ----------------------
        if ((aliveW[t >> 5] >> (t & 31)) & 1u) {
            int p = rowPtr[t]; int c = rowHead[t];
            bool stale = (usedW[c >> 5] >> (c & 31)) & 1u;
            if (stale) {
                if (p == SENT) { int q = atomicAdd(&rqn, 1); rowQ[q] = (unsigned short)t; }
                else {
                    const int len = rowLen[t];
                    for (;;) {
                        ++p;
                        if (p >= len) { p = SENT; int q = atomicAdd(&rqn, 1); rowQ[q] = (unsigned short)t; break; }
                        c = rowList[t * K + p];
                        if (!((usedW[c >> 5] >> (c & 31)) & 1u)) { rowHead[t] = (unsigned short)c; break; }
                    }
                    rowPtr[t] = (unsigned char)p;
                }
            }
        }
        // ---- phase 2b: repair col heads (unused cols) ---------------------
        if (!((usedW[t >> 5] >> (t & 31)) & 1u)) {
            int p = colPtr[t]; int r = colHead[t];
            bool stale = !((aliveW[r >> 5] >> (r & 31)) & 1u);
            if (stale) {
                if (p == SENT) { int q = atomicAdd(&cqn, 1); colQ[q] = (unsigned short)t; }
                else {
                    const int len = colLen[t];
                    for (;;) {
                        ++p;
                        if (p >= len) { p = SENT; int q = atomicAdd(&cqn, 1); colQ[q] = (unsigned short)t; break; }
                        r = colList[t * K + p];
                        if ((aliveW[r >> 5] >> (r & 31)) & 1u) { colHead[t] = (unsigned short)r; break; }
                    }
                    colPtr[t] = (unsigned char)p;
                }
            }
        }
        __syncthreads();                                           // B2

        // ---- phase 3: wave-parallel rescan + refill (no inner barriers) ---
        const int nr = rqn, nc = cqn;
        const unsigned umU = (usedW[lane >> 1] >> ((lane & 1) << 4)) & 0xFFFFu;
        const unsigned umA = (aliveW[lane >> 1] >> ((lane & 1) << 4)) & 0xFFFFu;
        const int len = aliveCnt < RF ? aliveCnt : RF;

        for (int i = wave; i < nr; i += 16) {        // rows: coalesced from C
            const int r = rowQ[i];
            const float4* rp = (const float4*)(C + (size_t)r * N) + (lane << 2);
            float4 q0 = rp[0], q1 = rp[1], q2 = rp[2], q3 = rp[3];
            float v[16] = {q0.x, q0.y, q0.z, q0.w, q1.x, q1.y, q1.z, q1.w,
                           q2.x, q2.y, q2.z, q2.w, q3.x, q3.y, q3.z, q3.w};
            unsigned excl = umU;
            int head0 = 0;
            for (int pass = 0; pass < len; ++pass) {
                float bv = -INFINITY; int bc = N;
                #pragma unroll
                for (int k = 0; k < 16; ++k) {
                    float vv = ((excl >> k) & 1u) ? -INFINITY : v[k];
                    if (vv > bv) { bv = vv; bc = (lane << 4) + k; }
                }
                wave_argmax(bv, bc);
                if (lane == (bc >> 4)) excl |= 1u << (bc & 15);
                if (pass == 0) head0 = bc;
                if (lane == 0) rowList[r * K + pass] = (unsigned short)bc;
            }
            if (lane == 0) {
                rowHead[r] = (unsigned short)head0;
                rowPtr[r] = 0;
                rowLen[r] = (unsigned char)len;
            }
        }

        if (haveCT) {
            for (int i = wave; i < nc; i += 16) {    // cols: coalesced from CT
                const int c = colQ[i];
                const float4* cp = (const float4*)(CT + (size_t)c * N) + (lane << 2);
                float4 q0 = cp[0], q1 = cp[1], q2 = cp[2], q3 = cp[3];
                float v[16] = {q0.x, q0.y, q0.z, q0.w, q1.x, q1.y, q1.z, q1.w,
                               q2.x, q2.y, q2.z, q2.w, q3.x, q3.y, q3.z, q3.w};
                unsigned excl = ~umA & 0xFFFFu;
                int head0 = 0;
                for (int pass = 0; pass < len; ++pass) {
                    float bv = -INFINITY; int br = N;
                    #pragma unroll
                    for (int k = 0; k < 16; ++k) {
                        float vv = ((excl >> k) & 1u) ? -INFINITY : v[k];
                        if (vv > bv) { bv = vv; br = (lane << 4) + k; }
                    }
                    wave_argmax(bv, br);
                    if (lane == (br >> 4)) excl |= 1u << (br & 15);
                    if (pass == 0) head0 = br;
                    if (lane == 0) colList[c * K + pass] = (unsigned short)br;
                }
                if (lane == 0) {
                    colHead[c] = (unsigned short)head0;
                    colPtr[c] = 0;
                    colLen[c] = (unsigned char)len;
                }
            }
        } else {
            for (int i = wave; i < nc; i += 16) {    // cols: strided gather, head only
                const int c = colQ[i];
                float bv = -INFINITY; int br = N;
                #pragma unroll
                for (int k = 0; k < 16; ++k) {
                    const int r = (k << 6) + lane;
                    bool a = (aliveW[(k << 1) + (lane >> 5)] >> (lane & 31)) & 1u;
                    float vv = a ? C[(size_t)r * N + c] : -INFINITY;
                    if (vv > bv) { bv = vv; br = r; }
                }
                wave_argmax(bv, br);
                if (lane == 0) colHead[c] = (unsigned short)br;   // ptr stays SENT
            }
        }
        __syncthreads();                                           // B3
    }

    out[t] = t;   // row-index half: identity
}

// ---------------------------------------------------------------------------
// Fallback (tiny ws): self-contained rounds kernel (alive-list full rescan).
// ---------------------------------------------------------------------------
__device__ __forceinline__ unsigned ordf(unsigned u) {
    return u ^ (unsigned)(((int)u >> 31) | (int)0x80000000);
}
__global__ __launch_bounds__(1024) void rounds_fallback(const float* __restrict__ C,
                                                        int* __restrict__ out) {
    __shared__ unsigned long long ck[N];
    __shared__ unsigned rbc[N];
    __shared__ unsigned short aliveList[2][N];
    __shared__ unsigned colUsedW[N / 32];
    __shared__ int cnts[2];
    const int tid = threadIdx.x;
    const int lane = tid & 63;
    const int wave = tid >> 6;
    aliveList[0][tid] = (unsigned short)tid;
    if (tid < N / 32) colUsedW[tid] = 0u;
    if (tid == 0) { cnts[0] = N; cnts[1] = 0; }
    __syncthreads();
    int p = 0;
    for (int round = 0; round < N + 2; ++round) {
        const int cnt = cnts[p];
        ck[tid] = 0ULL;
        if (tid == 0) cnts[p ^ 1] = 0;
        __syncthreads();
        const unsigned um = (colUsedW[lane >> 1] >> ((lane & 1) << 4)) & 0xFFFFu;
        unsigned cHi[16]; unsigned cRow[16];
        #pragma unroll
        for (int k = 0; k < 16; ++k) { cHi[k] = 0u; cRow[k] = 0u; }
        bool any = false;
        for (int i = wave; i < cnt; i += 16) {
            const int r = aliveList[p][i];
            any = true;
            const float4* rp = (const float4*)(C + (size_t)r * N) + (lane << 2);
            float4 q0 = rp[0], q1 = rp[1], q2 = rp[2], q3 = rp[3];
            float v[16] = {q0.x, q0.y, q0.z, q0.w, q1.x, q1.y, q1.z, q1.w,
                           q2.x, q2.y, q2.z, q2.w, q3.x, q3.y, q3.z, q3.w};
            float bv = -INFINITY; int bc = 0;
            #pragma unroll
            for (int k = 0; k < 16; ++k) {
                unsigned ou = ordf(__float_as_uint(v[k]));
                if (ou > cHi[k] || (ou == cHi[k] && (unsigned)r < cRow[k])) {
                    cHi[k] = ou; cRow[k] = (unsigned)r;
                }
                float vv = ((um >> k) & 1u) ? -INFINITY : v[k];
                if (vv > bv) { bv = vv; bc = (lane << 4) + k; }
            }
            wave_argmax(bv, bc);
            if (lane == 0) rbc[r] = (unsigned)bc;
        }
        if (any) {
            #pragma unroll
            for (int k = 0; k < 16; ++k)
                atomicMax(&ck[(k << 6) | lane],
                          ((unsigned long long)cHi[k] << 32) |
                          (unsigned long long)(N - 1 - cRow[k]));
        }
        __syncthreads();
        if (tid < cnt) {
            const int r = aliveList[p][tid];
            const int c = (int)rbc[r];
            const unsigned long long k64 = ck[((c & 15) << 6) | (c >> 4)];
            const int winner = (N - 1) - (int)(unsigned)(k64 & 0xFFFFFFFFull);
            if (winner == r) {
                out[N + r] = c;
                atomicOr(&colUsedW[c >> 5], 1u << (c & 31));
            } else {
                int idx = atomicAdd(&cnts[p ^ 1], 1);
                aliveList[p ^ 1][idx] = (unsigned short)r;
            }
        }
        __syncthreads();
        p ^= 1;
        if (cnts[p] == 0) break;
    }
    out[tid] = tid;
}

// ---------------------------------------------------------------------------
extern "C" void kernel_launch(void* const* d_in, const int* in_sizes, int n_in,
                              void* d_out, int out_size, void* d_ws, size_t ws_size,
                              hipStream_t stream) {
    const float* C = (const float*)d_in[0];
    int* out = (int*)d_out;

    const size_t listBytes = (size_t)2 * N * K * sizeof(unsigned short);  // 64 KB
    const size_t ctBytes   = (size_t)N * N * sizeof(float);               // 4 MB

    if (ws_size >= listBytes + ctBytes) {
        unsigned short* rowListG = (unsigned short*)d_ws;
        unsigned short* colListG = rowListG + N * K;
        float* CT = (float*)((char*)d_ws + listBytes);
        topk_kernel<<<256, 256, 0, stream>>>(C, rowListG);
        transpose_k<<<dim3(16, 16), 256, 0, stream>>>(C, CT);
        topk_kernel<<<256, 256, 0, stream>>>(CT, colListG);
        rounds_fast<<<1, 1024, 0, stream>>>(C, CT, rowListG, colListG, out, 1);
    } else if (ws_size >= listBytes) {
        unsigned short* rowListG = (unsigned short*)d_ws;
        unsigned short* colListG = rowListG + N * K;
        topk_kernel<<<256, 256, 0, stream>>>(C, rowListG);
        topk_cols<<<64, 1024, 0, stream>>>(C, colListG);
        rounds_fast<<<1, 1024, 0, stream>>>(C, C, rowListG, colListG, out, 0);
    } else {
        rounds_fallback<<<1, 1024, 0, stream>>>(C, out);
    }
}

// Round 10
// 78.327 us; speedup vs baseline: 2.2084x; 2.2084x over previous
//
#include <hip/hip_runtime.h>
#include <math.h>

#define N 1024
#define K 16
#define SENT 255

// (v2,f2) beats (v1,f1): larger value wins; tie -> smaller index
__device__ __forceinline__ bool better(float v2, int f2, float v1, int f1) {
    return (v2 > v1) || (v2 == v1 && f2 < f1);
}

// One reduce level via DPP (VALU latency, no DS pipe).
template<int CTRL>
__device__ __forceinline__ void dpp_step(float& v, int& f) {
    int ovi = __builtin_amdgcn_update_dpp(0, __float_as_int(v), CTRL, 0xF, 0xF, true);
    int ofi = __builtin_amdgcn_update_dpp(0, f, CTRL, 0xF, 0xF, true);
    float ov = __int_as_float(ovi);
    if (better(ov, ofi, v, f)) { v = ov; f = ofi; }
}

// Full-wave argmax on (v,f); result broadcast to all lanes.
__device__ __forceinline__ void wave_argmax(float& v, int& f) {
    dpp_step<0xB1>(v, f);
    dpp_step<0x4E>(v, f);
    dpp_step<0x141>(v, f);
    dpp_step<0x140>(v, f);
    float v0 = __int_as_float(__builtin_amdgcn_readlane(__float_as_int(v), 0));
    int   f0 = __builtin_amdgcn_readlane(f, 0);
    float v1 = __int_as_float(__builtin_amdgcn_readlane(__float_as_int(v), 16));
    int   f1 = __builtin_amdgcn_readlane(f, 16);
    float v2 = __int_as_float(__builtin_amdgcn_readlane(__float_as_int(v), 32));
    int   f2 = __builtin_amdgcn_readlane(f, 32);
    float v3 = __int_as_float(__builtin_amdgcn_readlane(__float_as_int(v), 48));
    int   f3 = __builtin_amdgcn_readlane(f, 48);
    if (better(v1, f1, v0, f0)) { v0 = v1; f0 = f1; }
    if (better(v3, f3, v2, f2)) { v2 = v3; f2 = f3; }
    if (better(v2, f2, v0, f0)) { v0 = v2; f0 = f2; }
    v = v0; f = f0;
}

// ---------------------------------------------------------------------------
// Tiled transpose C -> CT (64x64 tiles via LDS).
// ---------------------------------------------------------------------------
__global__ __launch_bounds__(256) void transpose_k(const float* __restrict__ C,
                                                   float* __restrict__ CT) {
    __shared__ float T[64][65];
    const int t = threadIdx.x;
    const int tx = t & 63, ty = t >> 6;
    const int bi = blockIdx.x, bj = blockIdx.y;
    #pragma unroll
    for (int k = 0; k < 16; ++k) {
        int r = (bi << 6) + ty + (k << 2);
        T[ty + (k << 2)][tx] = C[(size_t)r * N + (bj << 6) + tx];
    }
    __syncthreads();
    #pragma unroll
    for (int k = 0; k < 16; ++k) {
        int c = (bj << 6) + ty + (k << 2);
        CT[(size_t)c * N + (bi << 6) + tx] = T[tx][ty + (k << 2)];
    }
}

// ---------------------------------------------------------------------------
// Merged top-K: waves 0..1023 scan C rows -> rowList; waves 1024..2047 scan
// CT rows -> colList. (val desc, idx asc). One wave per row, coalesced.
// ---------------------------------------------------------------------------
__global__ __launch_bounds__(256) void topk_both(const float* __restrict__ C,
                                                 const float* __restrict__ CT,
                                                 unsigned short* __restrict__ rowListG,
                                                 unsigned short* __restrict__ colListG) {
    int gw   = (blockIdx.x * blockDim.x + threadIdx.x) >> 6;
    int lane = threadIdx.x & 63;
    const float* M;
    unsigned short* listG;
    int row;
    if (gw < N) { M = C;  listG = rowListG; row = gw; }
    else        { M = CT; listG = colListG; row = gw - N; }
    const float* rp = M + (size_t)row * N;
    float rv[16];
    #pragma unroll
    for (int k = 0; k < 16; ++k) rv[k] = rp[(k << 6) + lane];
    unsigned excl = 0;
    for (int pass = 0; pass < K; ++pass) {
        float best = -INFINITY; int bc = N;
        #pragma unroll
        for (int k = 0; k < 16; ++k) {
            int c = (k << 6) + lane;
            if (!((excl >> k) & 1u) && rv[k] > best) { best = rv[k]; bc = c; }
        }
        wave_argmax(best, bc);
        if (lane == (bc & 63)) excl |= 1u << (bc >> 6);
        if (lane == 0) listG[row * K + pass] = (unsigned short)bc;
    }
}

// ---------------------------------------------------------------------------
// Legacy col top-K via LDS tiles (used only when ws too small for CT).
// ---------------------------------------------------------------------------
__global__ __launch_bounds__(1024) void topk_cols(const float* __restrict__ C,
                                                  unsigned short* __restrict__ colListG) {
    __shared__ float T[16][1025];
    const int t  = threadIdx.x;
    const int c0 = blockIdx.x << 4;
    const int cc = t & 15;
    const int tr = t >> 4;
    #pragma unroll
    for (int k = 0; k < 16; ++k) {
        int r = (k << 6) + tr;
        T[cc][r] = C[(size_t)r * N + c0 + cc];
    }
    __syncthreads();
    const int wave = t >> 6;
    const int lane = t & 63;
    const int c = c0 + wave;
    float rv[16];
    #pragma unroll
    for (int k = 0; k < 16; ++k) rv[k] = T[wave][(k << 6) + lane];
    unsigned excl = 0;
    for (int pass = 0; pass < K; ++pass) {
        float best = -INFINITY; int br = N;
        #pragma unroll
        for (int k = 0; k < 16; ++k) {
            int r = (k << 6) + lane;
            if (!((excl >> k) & 1u) && rv[k] > best) { best = rv[k]; br = r; }
        }
        wave_argmax(best, br);
        if (lane == (br & 63)) excl |= 1u << (br >> 6);
        if (lane == 0) colListG[c * K + pass] = (unsigned short)br;
    }
}

// ---------------------------------------------------------------------------
// Standalone row top-K (fallback path only).
// ---------------------------------------------------------------------------
__global__ __launch_bounds__(256) void topk_kernel(const float* __restrict__ M,
                                                   unsigned short* __restrict__ listG) {
    int row  = (blockIdx.x * blockDim.x + threadIdx.x) >> 6;
    int lane = threadIdx.x & 63;
    if (row >= N) return;
    const float* rp = M + (size_t)row * N;
    float rv[16];
    #pragma unroll
    for (int k = 0; k < 16; ++k) rv[k] = rp[(k << 6) + lane];
    unsigned excl = 0;
    for (int pass = 0; pass < K; ++pass) {
        float best = -INFINITY; int bc = N;
        #pragma unroll
        for (int k = 0; k < 16; ++k) {
            int c = (k << 6) + lane;
            if (!((excl >> k) & 1u) && rv[k] > best) { best = rv[k]; bc = c; }
        }
        wave_argmax(best, bc);
        if (lane == (bc & 63)) excl |= 1u << (bc >> 6);
        if (lane == 0) listG[row * K + pass] = (unsigned short)bc;
    }
}

// ---------------------------------------------------------------------------
// Rounds (R8 version, head-only rescans): match mutual heads; pop dead heads
// from LDS lists; wave-parallel coalesced rescans (rows from C, cols from CT)
// on list exhaustion.
// ---------------------------------------------------------------------------
__global__ __launch_bounds__(1024) void rounds_fast(const float* __restrict__ C,
                                                    const float* __restrict__ CT,
                                                    const unsigned short* __restrict__ rowListG,
                                                    const unsigned short* __restrict__ colListG,
                                                    int* __restrict__ out,
                                                    int haveCT) {
    __shared__ unsigned short rowList[N * K];   // 32 KB
    __shared__ unsigned short colList[N * K];   // 32 KB
    __shared__ unsigned short rowHead[N];
    __shared__ unsigned short colHead[N];
    __shared__ unsigned char  rowPtr[N], colPtr[N];
    __shared__ unsigned aliveW[N / 32], usedW[N / 32];
    __shared__ unsigned short rowQ[N], colQ[N];
    __shared__ int rqn, cqn, matched;

    const int t = threadIdx.x;
    const int lane = t & 63;
    const int wave = t >> 6;

    #pragma unroll
    for (int i = 0; i < (N * K * 2) / (16 * 1024); ++i) {
        ((uint4*)rowList)[i * 1024 + t] = ((const uint4*)rowListG)[i * 1024 + t];
        ((uint4*)colList)[i * 1024 + t] = ((const uint4*)colListG)[i * 1024 + t];
    }
    rowPtr[t] = 0; colPtr[t] = 0;
    if (t < N / 32) { aliveW[t] = 0xFFFFFFFFu; usedW[t] = 0u; }
    if (t == 0) matched = 0;
    __syncthreads();
    rowHead[t] = rowList[t * K];
    colHead[t] = colList[t * K];
    __syncthreads();

    for (int round = 0; round < N + 8; ++round) {
        // ---- phase 1: match mutual-best pairs -----------------------------
        if ((aliveW[t >> 5] >> (t & 31)) & 1u) {
            const int c = rowHead[t];
            if ((int)colHead[c] == t) {
                out[N + t] = c;
                atomicAnd(&aliveW[t >> 5], ~(1u << (t & 31)));
                atomicOr(&usedW[c >> 5], 1u << (c & 31));
                atomicAdd(&matched, 1);
            }
        }
        if (t == 0) { rqn = 0; cqn = 0; }
        __syncthreads();                                           // B1
        if (matched >= N) break;

        // ---- phase 2a: repair row heads (alive rows) ----------------------
        if ((aliveW[t >> 5] >> (t & 31)) & 1u) {
            int p = rowPtr[t]; int c = rowHead[t];
            bool stale = (usedW[c >> 5] >> (c & 31)) & 1u;
            if (stale) {
                if (p == SENT) { int q = atomicAdd(&rqn, 1); rowQ[q] = (unsigned short)t; }
                else {
                    for (;;) {
                        ++p;
                        if (p >= K) { p = SENT; int q = atomicAdd(&rqn, 1); rowQ[q] = (unsigned short)t; break; }
                        c = rowList[t * K + p];
                        if (!((usedW[c >> 5] >> (c & 31)) & 1u)) { rowHead[t] = (unsigned short)c; break; }
                    }
                    rowPtr[t] = (unsigned char)p;
                }
            }
        }
        // ---- phase 2b: repair col heads (unused cols) ---------------------
        if (!((usedW[t >> 5] >> (t & 31)) & 1u)) {
            int p = colPtr[t]; int r = colHead[t];
            bool stale = !((aliveW[r >> 5] >> (r & 31)) & 1u);
            if (stale) {
                if (p == SENT) { int q = atomicAdd(&cqn, 1); colQ[q] = (unsigned short)t; }
                else {
                    for (;;) {
                        ++p;
                        if (p >= K) { p = SENT; int q = atomicAdd(&cqn, 1); colQ[q] = (unsigned short)t; break; }
                        r = colList[t * K + p];
                        if ((aliveW[r >> 5] >> (r & 31)) & 1u) { colHead[t] = (unsigned short)r; break; }
                    }
                    colPtr[t] = (unsigned char)p;
                }
            }
        }
        __syncthreads();                                           // B2

        // ---- phase 3: wave-parallel rescans (no inner barriers) -----------
        const int nr = rqn, nc = cqn;
        const unsigned umU = (usedW[lane >> 1] >> ((lane & 1) << 4)) & 0xFFFFu;
        const unsigned umA = (aliveW[lane >> 1] >> ((lane & 1) << 4)) & 0xFFFFu;

        for (int i = wave; i < nr; i += 16) {        // rows: coalesced from C
            const int r = rowQ[i];
            const float4* rp = (const float4*)(C + (size_t)r * N) + (lane << 2);
            float4 q0 = rp[0], q1 = rp[1], q2 = rp[2], q3 = rp[3];
            float v[16] = {q0.x, q0.y, q0.z, q0.w, q1.x, q1.y, q1.z, q1.w,
                           q2.x, q2.y, q2.z, q2.w, q3.x, q3.y, q3.z, q3.w};
            float bv = -INFINITY; int bc = N;
            #pragma unroll
            for (int k = 0; k < 16; ++k) {
                float vv = ((umU >> k) & 1u) ? -INFINITY : v[k];
                if (vv > bv) { bv = vv; bc = (lane << 4) + k; }
            }
            wave_argmax(bv, bc);
            if (lane == 0) rowHead[r] = (unsigned short)bc;
        }

        if (haveCT) {
            for (int i = wave; i < nc; i += 16) {    // cols: coalesced from CT
                const int c = colQ[i];
                const float4* cp = (const float4*)(CT + (size_t)c * N) + (lane << 2);
                float4 q0 = cp[0], q1 = cp[1], q2 = cp[2], q3 = cp[3];
                float v[16] = {q0.x, q0.y, q0.z, q0.w, q1.x, q1.y, q1.z, q1.w,
                               q2.x, q2.y, q2.z, q2.w, q3.x, q3.y, q3.z, q3.w};
                float bv = -INFINITY; int br = N;
                #pragma unroll
                for (int k = 0; k < 16; ++k) {
                    float vv = ((umA >> k) & 1u) ? v[k] : -INFINITY;
                    if (vv > bv) { bv = vv; br = (lane << 4) + k; }
                }
                wave_argmax(bv, br);
                if (lane == 0) colHead[c] = (unsigned short)br;
            }
        } else {
            for (int i = wave; i < nc; i += 16) {    // cols: strided gather
                const int c = colQ[i];
                float bv = -INFINITY; int br = N;
                #pragma unroll
                for (int k = 0; k < 16; ++k) {
                    const int r = (k << 6) + lane;
                    bool a = (aliveW[(k << 1) + (lane >> 5)] >> (lane & 31)) & 1u;
                    float vv = a ? C[(size_t)r * N + c] : -INFINITY;
                    if (vv > bv) { bv = vv; br = r; }
                }
                wave_argmax(bv, br);
                if (lane == 0) colHead[c] = (unsigned short)br;
            }
        }
        __syncthreads();                                           // B3
    }

    out[t] = t;   // row-index half: identity
}

// ---------------------------------------------------------------------------
// Fallback (tiny ws): self-contained rounds kernel (alive-list full rescan).
// ---------------------------------------------------------------------------
__device__ __forceinline__ unsigned ordf(unsigned u) {
    return u ^ (unsigned)(((int)u >> 31) | (int)0x80000000);
}
__global__ __launch_bounds__(1024) void rounds_fallback(const float* __restrict__ C,
                                                        int* __restrict__ out) {
    __shared__ unsigned long long ck[N];
    __shared__ unsigned rbc[N];
    __shared__ unsigned short aliveList[2][N];
    __shared__ unsigned colUsedW[N / 32];
    __shared__ int cnts[2];
    const int tid = threadIdx.x;
    const int lane = tid & 63;
    const int wave = tid >> 6;
    aliveList[0][tid] = (unsigned short)tid;
    if (tid < N / 32) colUsedW[tid] = 0u;
    if (tid == 0) { cnts[0] = N; cnts[1] = 0; }
    __syncthreads();
    int p = 0;
    for (int round = 0; round < N + 2; ++round) {
        const int cnt = cnts[p];
        ck[tid] = 0ULL;
        if (tid == 0) cnts[p ^ 1] = 0;
        __syncthreads();
        const unsigned um = (colUsedW[lane >> 1] >> ((lane & 1) << 4)) & 0xFFFFu;
        unsigned cHi[16]; unsigned cRow[16];
        #pragma unroll
        for (int k = 0; k < 16; ++k) { cHi[k] = 0u; cRow[k] = 0u; }
        bool any = false;
        for (int i = wave; i < cnt; i += 16) {
            const int r = aliveList[p][i];
            any = true;
            const float4* rp = (const float4*)(C + (size_t)r * N) + (lane << 2);
            float4 q0 = rp[0], q1 = rp[1], q2 = rp[2], q3 = rp[3];
            float v[16] = {q0.x, q0.y, q0.z, q0.w, q1.x, q1.y, q1.z, q1.w,
                           q2.x, q2.y, q2.z, q2.w, q3.x, q3.y, q3.z, q3.w};
            float bv = -INFINITY; int bc = 0;
            #pragma unroll
            for (int k = 0; k < 16; ++k) {
                unsigned ou = ordf(__float_as_uint(v[k]));
                if (ou > cHi[k] || (ou == cHi[k] && (unsigned)r < cRow[k])) {
                    cHi[k] = ou; cRow[k] = (unsigned)r;
                }
                float vv = ((um >> k) & 1u) ? -INFINITY : v[k];
                if (vv > bv) { bv = vv; bc = (lane << 4) + k; }
            }
            wave_argmax(bv, bc);
            if (lane == 0) rbc[r] = (unsigned)bc;
        }
        if (any) {
            #pragma unroll
            for (int k = 0; k < 16; ++k)
                atomicMax(&ck[(k << 6) | lane],
                          ((unsigned long long)cHi[k] << 32) |
                          (unsigned long long)(N - 1 - cRow[k]));
        }
        __syncthreads();
        if (tid < cnt) {
            const int r = aliveList[p][tid];
            const int c = (int)rbc[r];
            const unsigned long long k64 = ck[((c & 15) << 6) | (c >> 4)];
            const int winner = (N - 1) - (int)(unsigned)(k64 & 0xFFFFFFFFull);
            if (winner == r) {
                out[N + r] = c;
                atomicOr(&colUsedW[c >> 5], 1u << (c & 31));
            } else {
                int idx = atomicAdd(&cnts[p ^ 1], 1);
                aliveList[p ^ 1][idx] = (unsigned short)r;
            }
        }
        __syncthreads();
        p ^= 1;
        if (cnts[p] == 0) break;
    }
    out[tid] = tid;
}

// ---------------------------------------------------------------------------
extern "C" void kernel_launch(void* const* d_in, const int* in_sizes, int n_in,
                              void* d_out, int out_size, void* d_ws, size_t ws_size,
                              hipStream_t stream) {
    const float* C = (const float*)d_in[0];
    int* out = (int*)d_out;

    const size_t listBytes = (size_t)2 * N * K * sizeof(unsigned short);  // 64 KB
    const size_t ctBytes   = (size_t)N * N * sizeof(float);               // 4 MB

    if (ws_size >= listBytes + ctBytes) {
        unsigned short* rowListG = (unsigned short*)d_ws;
        unsigned short* colListG = rowListG + N * K;
        float* CT = (float*)((char*)d_ws + listBytes);
        transpose_k<<<dim3(16, 16), 256, 0, stream>>>(C, CT);
        topk_both<<<512, 256, 0, stream>>>(C, CT, rowListG, colListG);
        rounds_fast<<<1, 1024, 0, stream>>>(C, CT, rowListG, colListG, out, 1);
    } else if (ws_size >= listBytes) {
        unsigned short* rowListG = (unsigned short*)d_ws;
        unsigned short* colListG = rowListG + N * K;
        topk_kernel<<<256, 256, 0, stream>>>(C, rowListG);
        topk_cols<<<64, 1024, 0, stream>>>(C, colListG);
        rounds_fast<<<1, 1024, 0, stream>>>(C, C, rowListG, colListG, out, 0);
    } else {
        rounds_fallback<<<1, 1024, 0, stream>>>(C, out);
    }
}